// Round 5
// baseline (173.923 us; speedup 1.0000x reference)
//
#include <hip/hip_runtime.h>

#define EPS 1e-6

constexpr int B = 8, C = 256, T = 16000;
constexpr int T4 = T / 4;            // 4000
constexpr int NBLK = 125;            // blocks per batch
constexpr int TPB_T = 128;           // t-columns per block
constexpr int NT4 = 32;              // float4 groups per block (128/4)

#define F_EMPTY 0u
#define F_AGG   1u
#define F_PRE   2u

// Fused single-pass: per-block channel sums -> block scan -> decoupled-lookback
// cross-block prefix -> normalize (x re-read is L2-hot; R3 measured FETCH =
// x-read-once). R3's 200us pathology attributed to ACQUIRE-per-poll-iteration
// in the lookback spin (agent-scope acquire => cache-invalidate storm).
// Fix: RELAXED polls + s_sleep backoff + ONE __threadfence() per window.
__global__ __launch_bounds__(256)
void clnorm_fused(const float4* __restrict__ x4,
                  const float*  __restrict__ weight,
                  const float*  __restrict__ bias,
                  float4* __restrict__ y4,
                  unsigned int* __restrict__ flags,    // [B*NBLK], zeroed per call
                  unsigned int* __restrict__ counter,  // [1], zeroed per call
                  double2* __restrict__ agg,           // [B*NBLK]
                  double2* __restrict__ pref)          // [B*NBLK]
{
    __shared__ unsigned int sid;
    const int tid  = threadIdx.x;
    const int lane = tid & 63;
    const int wid  = tid >> 6;
    if (tid == 0) sid = atomicAdd(counter, 1u);
    __syncthreads();
    const int id  = (int)sid;
    const int b   = id / NBLK;
    const int blk = id % NBLK;
    const int gb  = id;               // == b*NBLK + blk
    const int t4base = blk * NT4;

    const int t4 = tid & 31;          // float4 group within block
    const int c0 = tid >> 5;          // 0..7, c stride 8

    const size_t xrow = (size_t)b * C;

    // ---- Phase A: per-t sums over channels (float4 over t) ----
    float4 s4 = {0.f,0.f,0.f,0.f}, q4 = {0.f,0.f,0.f,0.f};
#pragma unroll 8
    for (int i = 0; i < 32; ++i) {
        int c = c0 + 8 * i;
        float4 xv = x4[(xrow + c) * T4 + t4base + t4];
        s4.x += xv.x;       s4.y += xv.y;       s4.z += xv.z;       s4.w += xv.w;
        q4.x += xv.x*xv.x;  q4.y += xv.y*xv.y;  q4.z += xv.z*xv.z;  q4.w += xv.w*xv.w;
    }

    __shared__ float psum[8 * TPB_T], qsum[8 * TPB_T];
    ((float4*)psum)[c0 * NT4 + t4] = s4;
    ((float4*)qsum)[c0 * NT4 + t4] = q4;
    __syncthreads();

    // ---- block-local inclusive scan over 128 t values (double) ----
    __shared__ double csum[TPB_T], csum2[TPB_T];
    __shared__ double wtot[2], wtot2[2];
    double ds = 0.0, dq = 0.0;
    if (tid < TPB_T) {
        float fs = 0.f, fq = 0.f;
#pragma unroll
        for (int g = 0; g < 8; ++g) {
            fs += psum[g * TPB_T + tid];
            fq += qsum[g * TPB_T + tid];
        }
        ds = (double)fs; dq = (double)fq;
        for (int off = 1; off < 64; off <<= 1) {
            double u  = __shfl_up(ds, off);
            double u2 = __shfl_up(dq, off);
            if (lane >= off) { ds += u; dq += u2; }
        }
        if (lane == 63) { wtot[wid] = ds; wtot2[wid] = dq; }
    }
    __syncthreads();
    if (tid < TPB_T) {
        if (wid == 1) { ds += wtot[0]; dq += wtot2[0]; }
        csum[tid] = ds; csum2[tid] = dq;
    }
    __syncthreads();

    const double aggS = wtot[0] + wtot[1];
    const double aggQ = wtot2[0] + wtot2[1];

    // ---- Phase B: publish aggregate, wave-parallel lookback (wave 0) ----
    // RELAXED spin; one __threadfence() per window before reading values.
    __shared__ double exsh[2];
    if (wid == 0) {
        if (lane == 0) {
            agg[gb] = make_double2(aggS, aggQ);
            __hip_atomic_store(&flags[gb], F_AGG, __ATOMIC_RELEASE,
                               __HIP_MEMORY_SCOPE_AGENT);
        }
        double exS = 0.0, exQ = 0.0;
        int hi = blk;                       // window = [hi-64, hi)
        while (hi > 0) {
            int  j  = hi - 64 + lane;
            bool v  = (j >= 0);
            int  fj = b * NBLK + j;
            unsigned int st = v ? __hip_atomic_load(&flags[fj], __ATOMIC_RELAXED,
                                                    __HIP_MEMORY_SCOPE_AGENT)
                                : F_PRE;
            while (__any(st == F_EMPTY)) {
                __builtin_amdgcn_s_sleep(4);
                if (v && st == F_EMPTY)
                    st = __hip_atomic_load(&flags[fj], __ATOMIC_RELAXED,
                                           __HIP_MEMORY_SCOPE_AGENT);
            }
            __threadfence();   // single acquire-equivalent fence per window
            unsigned long long pm = __ballot(v && st == F_PRE);
            double cS = 0.0, cQ = 0.0;
            bool last = false;
            if (pm) {
                int plane = 63 - __clzll(pm);   // highest (closest) PREFIX
                if (v && lane > plane) { double2 a = agg[fj];  cS = a.x; cQ = a.y; }
                if (lane == plane)     { double2 p = pref[fj]; cS = p.x; cQ = p.y; }
                last = true;
            } else {
                if (v) { double2 a = agg[fj]; cS = a.x; cQ = a.y; }
            }
            for (int o = 32; o; o >>= 1) { cS += __shfl_xor(cS, o); cQ += __shfl_xor(cQ, o); }
            exS += cS; exQ += cQ;
            if (last) break;
            hi -= 64;
        }
        if (lane == 0) {
            pref[gb] = make_double2(exS + aggS, exQ + aggQ);
            __hip_atomic_store(&flags[gb], F_PRE, __ATOMIC_RELEASE,
                               __HIP_MEMORY_SCOPE_AGENT);
            exsh[0] = exS; exsh[1] = exQ;
        }
    }
    __syncthreads();

    // ---- mean / istd for this block's 128 t values ----
    __shared__ float meanf[TPB_T], istdf[TPB_T];
    if (tid < TPB_T) {
        int t = blk * TPB_T + tid;
        double cs  = exsh[0] + csum[tid];
        double cq  = exsh[1] + csum2[tid];
        double cnt = (double)(t + 1) * (double)C;
        double mean = cs / cnt;
        double var  = cq / cnt - mean * mean;
        meanf[tid] = (float)mean;
        istdf[tid] = (float)(1.0 / sqrt(var + EPS));
    }
    __syncthreads();

    // ---- Phase C: normalize (x re-read is L2-hot) ----
    const float4 mv = ((const float4*)meanf)[t4];
    const float4 iv = ((const float4*)istdf)[t4];
#pragma unroll 4
    for (int i = 0; i < 32; ++i) {
        int c = c0 + 8 * i;
        size_t idx = (xrow + c) * T4 + t4base + t4;
        float4 xv = x4[idx];
        float w  = weight[c];
        float bb = bias[c];
        float4 o;
        o.x = w * (xv.x - mv.x) * iv.x + bb;
        o.y = w * (xv.y - mv.y) * iv.y + bb;
        o.z = w * (xv.z - mv.z) * iv.z + bb;
        o.w = w * (xv.w - mv.w) * iv.w + bb;
        y4[idx] = o;
    }
}

extern "C" void kernel_launch(void* const* d_in, const int* in_sizes, int n_in,
                              void* d_out, int out_size, void* d_ws, size_t ws_size,
                              hipStream_t stream) {
    const float* x      = (const float*)d_in[0];
    const float* weight = (const float*)d_in[1];
    const float* bias   = (const float*)d_in[2];
    float* y = (float*)d_out;

    unsigned int* flags   = (unsigned int*)d_ws;          // B*NBLK = 1000 uints
    unsigned int* counter = flags + B * NBLK;             // 1 uint @ byte 4000
    double2* agg  = (double2*)((char*)d_ws + 4096);       // 1000 double2
    double2* pref = agg + B * NBLK;                       // 1000 double2

    // zero flags + counter each call (graph-capturable async memset)
    hipMemsetAsync(d_ws, 0, 4096, stream);

    clnorm_fused<<<dim3(B * NBLK), 256, 0, stream>>>(
        (const float4*)x, weight, bias, (float4*)y, flags, counter, agg, pref);
}

// Round 6
// 74.017 us; speedup vs baseline: 2.3498x; 2.3498x over previous
//
#include <hip/hip_runtime.h>

#define EPS 1e-6

constexpr int B = 8, C = 256, T = 16000;
constexpr int T4 = T / 4;          // 4000, T divisible by 4
constexpr int BT = B * T;          // 128000

typedef float f32x4 __attribute__((ext_vector_type(4)));

// ---------------- Kernel 1: per-(b,t) channel sums ----------------
// grid (ceil(T/256), B), block 256. Lane-consecutive t => coalesced loads.
// Measured ~6.2 TB/s — at the read-only ceiling; do not touch.
__global__ __launch_bounds__(256)
void colsum_kernel(const float* __restrict__ x,
                   float* __restrict__ S, float* __restrict__ S2) {
    int b = blockIdx.y;
    int t = blockIdx.x * 256 + threadIdx.x;
    if (t >= T) return;
    const float* xp = x + (size_t)b * C * T + t;
    float s = 0.f, s2 = 0.f;
#pragma unroll 8
    for (int c = 0; c < C; ++c) {
        float v = xp[(size_t)c * T];
        s  += v;
        s2 += v * v;
    }
    S [b * T + t] = s;
    S2[b * T + t] = s2;
}

// ---------------- Kernel 2: per-b inclusive scan -> mean, istd ----------------
// One block per b, 1024 threads. Single-pass: 16 elems/thread local scan
// (double), wave shfl-scan of thread totals, LDS pass over 16 wave totals.
// ~3 us, latency-bound; leave alone.
__global__ __launch_bounds__(1024)
void scan_kernel(const float* __restrict__ S, const float* __restrict__ S2,
                 float* __restrict__ meanp, float* __restrict__ istdp) {
    constexpr int PT = 16;                 // elements per thread; 1000 active
    int b    = blockIdx.x;
    int tid  = threadIdx.x;
    int lane = tid & 63;
    int wid  = tid >> 6;                   // 0..15
    int t0   = tid * PT;
    bool active = (t0 < T);

    double v[PT], v2[PT];
    if (active) {
        const float4* Sp  = (const float4*)(S  + b * T + t0);
        const float4* S2p = (const float4*)(S2 + b * T + t0);
#pragma unroll
        for (int j = 0; j < PT / 4; ++j) {
            float4 a  = Sp[j];
            float4 a2 = S2p[j];
            v [4*j+0] = a.x;  v [4*j+1] = a.y;  v [4*j+2] = a.z;  v [4*j+3] = a.w;
            v2[4*j+0] = a2.x; v2[4*j+1] = a2.y; v2[4*j+2] = a2.z; v2[4*j+3] = a2.w;
        }
    } else {
#pragma unroll
        for (int j = 0; j < PT; ++j) { v[j] = 0.0; v2[j] = 0.0; }
    }

    // thread-local inclusive scan
#pragma unroll
    for (int j = 1; j < PT; ++j) { v[j] += v[j-1]; v2[j] += v2[j-1]; }
    double ts = v[PT-1], ts2 = v2[PT-1];

    // wave-64 inclusive scan of thread totals
    double s = ts, s2 = ts2;
    for (int off = 1; off < 64; off <<= 1) {
        double u  = __shfl_up(s,  off);
        double u2 = __shfl_up(s2, off);
        if (lane >= off) { s += u; s2 += u2; }
    }
    double waveExcl  = s  - ts;
    double waveExcl2 = s2 - ts2;

    __shared__ double wtot[16], wtot2[16];
    if (lane == 63) { wtot[wid] = s; wtot2[wid] = s2; }
    __syncthreads();

    double base = 0.0, base2 = 0.0;
    for (int w = 0; w < wid; ++w) { base += wtot[w]; base2 += wtot2[w]; }
    double off0  = base  + waveExcl;
    double off02 = base2 + waveExcl2;

    if (active) {
        float m[PT], is[PT];
#pragma unroll
        for (int j = 0; j < PT; ++j) {
            double cs   = off0  + v[j];
            double cs2  = off02 + v2[j];
            double cnt  = (double)(t0 + j + 1) * (double)C;
            double mean = cs / cnt;
            double var  = cs2 / cnt - mean * mean;
            double istd = 1.0 / sqrt(var + EPS);
            m [j] = (float)mean;
            is[j] = (float)istd;
        }
        float4* mp = (float4*)(meanp + b * T + t0);
        float4* ip = (float4*)(istdp + b * T + t0);
#pragma unroll
        for (int j = 0; j < PT / 4; ++j) {
            mp[j] = make_float4(m [4*j+0], m [4*j+1], m [4*j+2], m [4*j+3]);
            ip[j] = make_float4(is[4*j+0], is[4*j+1], is[4*j+2], is[4*j+3]);
        }
    }
}

// ---------------- Kernel 3: normalize, float4 over t ----------------
// Exact R2 structure (74.9 us proven) with ONE change: nontemporal store for
// y, so the 131 MB write stream does not allocate in L2/L3 and evict the
// L3-resident x (x 131 MB + y 131 MB > 256 MB L3) mid-kernel.
__global__ __launch_bounds__(256)
void norm_kernel(const float4* __restrict__ x4,
                 const float*  __restrict__ weight,
                 const float*  __restrict__ bias,
                 const float*  __restrict__ meanp,
                 const float*  __restrict__ istdp,
                 float4* __restrict__ y4) {
    int t4 = blockIdx.x * 256 + threadIdx.x;
    if (t4 >= T4) return;
    int c = blockIdx.y;
    int b = blockIdx.z;

    size_t idx = ((size_t)b * C + c) * T4 + t4;
    float4 xv = x4[idx];
    const float4 mv = *(const float4*)(meanp + (size_t)b * T + (size_t)t4 * 4);
    const float4 iv = *(const float4*)(istdp + (size_t)b * T + (size_t)t4 * 4);
    float w  = weight[c];
    float bb = bias[c];

    f32x4 o;
    o.x = w * (xv.x - mv.x) * iv.x + bb;
    o.y = w * (xv.y - mv.y) * iv.y + bb;
    o.z = w * (xv.z - mv.z) * iv.z + bb;
    o.w = w * (xv.w - mv.w) * iv.w + bb;
    __builtin_nontemporal_store(o, (f32x4*)&y4[idx]);
}

extern "C" void kernel_launch(void* const* d_in, const int* in_sizes, int n_in,
                              void* d_out, int out_size, void* d_ws, size_t ws_size,
                              hipStream_t stream) {
    const float* x      = (const float*)d_in[0];
    const float* weight = (const float*)d_in[1];
    const float* bias   = (const float*)d_in[2];
    float* y = (float*)d_out;

    float* S    = (float*)d_ws;          // BT floats
    float* S2   = S  + BT;               // BT floats
    float* mea  = S2 + BT;               // BT floats
    float* istd = mea + BT;              // BT floats  (total 2 MB)

    dim3 g1((T + 255) / 256, B);
    colsum_kernel<<<g1, 256, 0, stream>>>(x, S, S2);

    scan_kernel<<<B, 1024, 0, stream>>>(S, S2, mea, istd);

    dim3 g3((T4 + 255) / 256, C, B);
    norm_kernel<<<g3, 256, 0, stream>>>((const float4*)x, weight, bias,
                                        mea, istd, (float4*)y);
}